// Round 3
// baseline (574.813 us; speedup 1.0000x reference)
//
#include <hip/hip_runtime.h>

// Problem constants (fixed by reference setup_inputs)
#define BB   8
#define CCH  128
#define HH   256
#define WW   256
#define NHH  128
#define NWW  128

#define WPB  8           // windows per block (along nW)
#define TPB  128         // threads per block (2 waves)
#define TS   36          // tile row stride (16B-aligned; 9c mod 8 spreads quads)
#define QS   8           // qm/gl row stride (16B-aligned, 32B rows)

// Kernel 0: M[cp][c] = (1/sqrt(Cr)) * sum_r Wq[cp][r] * Wk[c][r]
__global__ void compute_m_kernel(const float* __restrict__ Wq,
                                 const float* __restrict__ Wk,
                                 float* __restrict__ M) {
    int idx = blockIdx.x * blockDim.x + threadIdx.x;   // 0..16383
    int cp = idx >> 7;
    int c  = idx & 127;
    float s = 0.f;
#pragma unroll
    for (int r = 0; r < 32; ++r)
        s += Wq[cp * 32 + r] * Wk[c * 32 + r];
    M[idx] = s * 0.17677669529663687f;   // 32^-0.5
}

// DPP quad-perm add (pure VALU cross-lane; ctrl must be a constant expr)
template <int CTRL>
__device__ __forceinline__ float dpp_add(float v) {
    int x = __builtin_amdgcn_update_dpp(0, __float_as_int(v), CTRL, 0xF, 0xF, true);
    return v + __int_as_float(x);
}

__global__ __launch_bounds__(TPB)
void attn_ds2(const float* __restrict__ fm, const float* __restrict__ M,
              float* __restrict__ out) {
    __shared__ float tile[CCH][TS];     // [c][r*16 + j], j=0..15 (16 input cols)
    __shared__ float qg[CCH][QS];       // qm (B..C), then gl (C-tail..E) — aliased
    __shared__ float4 attn4[WPB];       // per-window softmax weights

    const int wseg = blockIdx.x;        // 0..15
    const int nh   = blockIdx.y;        // 0..127
    const int b    = blockIdx.z;        // 0..7
    const int t    = threadIdx.x;       // 0..127

    const int w0   = wseg * 16;         // input column base (16 cols = 8 windows)
    const int row0 = nh * 2;            // input row base (2 rows)

    // ---------------- Phase A: stage 128c x 32 pixels (coalesced 64B segs) ----
#pragma unroll
    for (int k = 0; k < 8; ++k) {
        int q = k * TPB + t;            // float4 index 0..1023
        int c = q >> 3;                 // 8 float4 per c-row
        int f = q & 7;
        int r = f >> 2, j = (f & 3) << 2;
        const float4 v = *reinterpret_cast<const float4*>(
            fm + (((size_t)(b * CCH + c) * HH + row0 + r) * WW + w0 + j));
        *reinterpret_cast<float4*>(&tile[c][r * 16 + j]) = v;
    }
    __syncthreads();

    // ---------------- Phase B: qm[c=t][w] = mean of 4 window pixels -----------
    {
        float p[32];
#pragma unroll
        for (int k = 0; k < 8; ++k)
            *reinterpret_cast<float4*>(&p[k * 4]) =
                *reinterpret_cast<const float4*>(&tile[t][k * 4]);
        float qa[4], qb[4];
#pragma unroll
        for (int w = 0; w < 4; ++w)
            qa[w] = 0.25f * (p[2*w] + p[2*w+1] + p[16+2*w] + p[16+2*w+1]);
#pragma unroll
        for (int w = 0; w < 4; ++w) {
            int ww = w + 4;
            qb[w] = 0.25f * (p[2*ww] + p[2*ww+1] + p[16+2*ww] + p[16+2*ww+1]);
        }
        *reinterpret_cast<float4*>(&qg[t][0]) = make_float4(qa[0], qa[1], qa[2], qa[3]);
        *reinterpret_cast<float4*>(&qg[t][4]) = make_float4(qb[0], qb[1], qb[2], qb[3]);
    }
    __syncthreads();

    // ---------------- Phase C: g[c][w] = sum_cp qm[cp][w] * M[cp][c] ----------
    // Thread (wave wv, lane l): cpg = l&3 (cp-slice, interleaved), cg = l>>2.
    // Owns c = wv*64 + cg*4 .. +3, all 8 windows, cp subset {4k+cpg}.
    {
        const int l   = t & 63;
        const int wv  = t >> 6;
        const int cpg = l & 3;
        const int cg  = l >> 2;
        const int c0  = wv * 64 + cg * 4;

        float acc[4][8];
#pragma unroll
        for (int i = 0; i < 4; ++i)
#pragma unroll
            for (int w = 0; w < 8; ++w) acc[i][w] = 0.f;

#pragma unroll 4
        for (int k = 0; k < 32; ++k) {
            int cp = 4 * k + cpg;
            const float4 m4 = *reinterpret_cast<const float4*>(M + cp * 128 + c0);
            const float4 qa = *reinterpret_cast<const float4*>(&qg[cp][0]);
            const float4 qb = *reinterpret_cast<const float4*>(&qg[cp][4]);
            const float mm[4] = {m4.x, m4.y, m4.z, m4.w};
            const float qq[8] = {qa.x, qa.y, qa.z, qa.w, qb.x, qb.y, qb.z, qb.w};
#pragma unroll
            for (int i = 0; i < 4; ++i)
#pragma unroll
                for (int w = 0; w < 8; ++w)
                    acc[i][w] += mm[i] * qq[w];
        }

        // quad-reduce over cpg (xor1 = quad_perm[1,0,3,2]=0xB1; xor2 = [2,3,0,1]=0x4E)
#pragma unroll
        for (int i = 0; i < 4; ++i)
#pragma unroll
            for (int w = 0; w < 8; ++w) {
                acc[i][w] = dpp_add<0xB1>(acc[i][w]);
                acc[i][w] = dpp_add<0x4E>(acc[i][w]);
            }

        // lane writes row c = c0 + cpg (branchless static select of acc[cpg][*])
        float row[8];
#pragma unroll
        for (int w = 0; w < 8; ++w) {
            float s01 = (cpg & 1) ? acc[1][w] : acc[0][w];
            float s23 = (cpg & 1) ? acc[3][w] : acc[2][w];
            row[w] = (cpg & 2) ? s23 : s01;
        }
        __syncthreads();   // all qm reads complete before overwrite
        *reinterpret_cast<float4*>(&qg[c0 + cpg][0]) =
            make_float4(row[0], row[1], row[2], row[3]);
        *reinterpret_cast<float4*>(&qg[c0 + cpg][4]) =
            make_float4(row[4], row[5], row[6], row[7]);
    }
    __syncthreads();

    // ---------------- Phase D: qk + softmax -> attn4 --------------------------
    {
        const int w = t >> 4;           // 0..7 across both waves
        const int tsub = t & 15;        // 16 lanes per window
        float qk0 = 0.f, qk1 = 0.f, qk2 = 0.f, qk3 = 0.f;
#pragma unroll
        for (int i = 0; i < 8; ++i) {
            int c = i * 16 + tsub;
            float g = qg[c][w];
            qk0 += g * tile[c][2 * w];
            qk1 += g * tile[c][2 * w + 1];
            qk2 += g * tile[c][16 + 2 * w];
            qk3 += g * tile[c][16 + 2 * w + 1];
        }
#pragma unroll
        for (int off = 1; off < 16; off <<= 1) {
            qk0 += __shfl_xor(qk0, off);
            qk1 += __shfl_xor(qk1, off);
            qk2 += __shfl_xor(qk2, off);
            qk3 += __shfl_xor(qk3, off);
        }
        float mx = fmaxf(fmaxf(qk0, qk1), fmaxf(qk2, qk3));
        float e0 = __expf(qk0 - mx);
        float e1 = __expf(qk1 - mx);
        float e2 = __expf(qk2 - mx);
        float e3 = __expf(qk3 - mx);
        float inv = 1.0f / (e0 + e1 + e2 + e3);
        if (tsub == 0)
            attn4[w] = make_float4(e0 * inv, e1 * inv, e2 * inv, e3 * inv);
    }
    __syncthreads();

    // ---------------- Phase E: out[c=t][w] = sum_tok attn * pixel -------------
    {
        float p[32];
#pragma unroll
        for (int k = 0; k < 8; ++k)
            *reinterpret_cast<float4*>(&p[k * 4]) =
                *reinterpret_cast<const float4*>(&tile[t][k * 4]);
        float o[8];
#pragma unroll
        for (int w = 0; w < 8; ++w) {
            const float4 a = attn4[w];
            o[w] = a.x * p[2*w] + a.y * p[2*w+1] + a.z * p[16+2*w] + a.w * p[16+2*w+1];
        }
        const size_t ob = (((size_t)(b * CCH + t) * NHH + nh) * NWW) + wseg * 8;
        *reinterpret_cast<float4*>(out + ob)     = make_float4(o[0], o[1], o[2], o[3]);
        *reinterpret_cast<float4*>(out + ob + 4) = make_float4(o[4], o[5], o[6], o[7]);
    }
}

extern "C" void kernel_launch(void* const* d_in, const int* in_sizes, int n_in,
                              void* d_out, int out_size, void* d_ws, size_t ws_size,
                              hipStream_t stream) {
    const float* fm = (const float*)d_in[0];
    const float* Wq = (const float*)d_in[1];
    const float* Wk = (const float*)d_in[2];
    float* outp = (float*)d_out;
    float* Mws  = (float*)d_ws;      // 128*128 floats = 64 KB

    compute_m_kernel<<<dim3(64), dim3(256), 0, stream>>>(Wq, Wk, Mws);

    dim3 grid(NWW / WPB, NHH, BB);   // (16, 128, 8)
    attn_ds2<<<grid, dim3(TPB), 0, stream>>>(fm, Mws, outp);
}

// Round 4
// 479.754 us; speedup vs baseline: 1.1981x; 1.1981x over previous
//
#include <hip/hip_runtime.h>

// Problem constants (fixed by reference setup_inputs)
#define BB   8
#define CCH  128
#define HH   256
#define WW   256
#define NHH  128
#define NWW  128

#define WPB  16          // windows per block (along nW) -> 64B-contiguous output runs
#define TPB  128         // 2 waves
#define TS   68          // tile row stride (floats): 16B-aligned rows, 64 used + 4 pad
#define QS   20          // g row stride: 16B-aligned; conflict-free phase-D reads

// Kernel 0: M[cp][c] = (1/sqrt(Cr)) * sum_r Wq[cp][r] * Wk[c][r]
__global__ void compute_m_kernel(const float* __restrict__ Wq,
                                 const float* __restrict__ Wk,
                                 float* __restrict__ M) {
    int idx = blockIdx.x * blockDim.x + threadIdx.x;   // 0..16383
    int cp = idx >> 7;
    int c  = idx & 127;
    float s = 0.f;
#pragma unroll
    for (int r = 0; r < 32; ++r)
        s += Wq[cp * 32 + r] * Wk[c * 32 + r];
    M[idx] = s * 0.17677669529663687f;   // 32^-0.5
}

__global__ __launch_bounds__(TPB)
void attn_ds3(const float* __restrict__ fm, const float* __restrict__ M,
              float* __restrict__ out) {
    __shared__ float tile[CCH][TS];     // [c][r*32 + j], j=0..31 (32 input cols)
    __shared__ float qg[CCH][QS];       // g[c][w] (written in C, read in D)
    __shared__ float4 attn4[WPB];       // per-window softmax weights

    const int wseg = blockIdx.x;        // 0..7
    const int nh   = blockIdx.y;        // 0..127
    const int b    = blockIdx.z;        // 0..7
    const int t    = threadIdx.x;       // 0..127
    const int l    = t & 63;            // lane
    const int wv   = t >> 6;            // wave (0,1) = w-half

    const int w0   = wseg * 32;         // input column base (32 cols = 16 windows)
    const int row0 = nh * 2;            // input row base (2 rows)

    // ---------------- Phase A: stage 128c x 64 pixels (reg-staged, coalesced) --
    const float* fmb = fm + ((size_t)(b * CCH) * HH + row0) * WW + w0;
#pragma unroll
    for (int k = 0; k < 16; ++k) {
        int q  = k * TPB + t;           // float4 index 0..2047
        int c  = q >> 4;                // 16 float4 per c-row
        int rj = (q & 15) << 2;         // 0..60
        int r  = rj >> 5;
        int j  = rj & 31;
        const float4 v = *reinterpret_cast<const float4*>(
            fmb + ((size_t)c * HH + r) * WW + j);
        *reinterpret_cast<float4*>(&tile[c][rj]) = v;
    }
    __syncthreads();

    // ---------------- Phase B: qmean rows l and l+64 for this wave's w-half ----
    // qm[w] = 0.25*(x[2w] + x[2w+1] + x[32+2w] + x[32+2w+1]), w-local 0..7.
    float qmA[8], qmB[8];
    {
        const int j0 = wv * 16;         // w-half h=wv -> j0..j0+15 (r0), 32+j0.. (r1)
        float p0[16], p1[16];
#pragma unroll
        for (int q = 0; q < 4; ++q) {
            *reinterpret_cast<float4*>(&p0[q * 4]) =
                *reinterpret_cast<const float4*>(&tile[l][j0 + q * 4]);
            *reinterpret_cast<float4*>(&p1[q * 4]) =
                *reinterpret_cast<const float4*>(&tile[l][32 + j0 + q * 4]);
        }
#pragma unroll
        for (int w = 0; w < 8; ++w)
            qmA[w] = 0.25f * (p0[2*w] + p0[2*w+1] + p1[2*w] + p1[2*w+1]);
#pragma unroll
        for (int q = 0; q < 4; ++q) {
            *reinterpret_cast<float4*>(&p0[q * 4]) =
                *reinterpret_cast<const float4*>(&tile[l + 64][j0 + q * 4]);
            *reinterpret_cast<float4*>(&p1[q * 4]) =
                *reinterpret_cast<const float4*>(&tile[l + 64][32 + j0 + q * 4]);
        }
#pragma unroll
        for (int w = 0; w < 8; ++w)
            qmB[w] = 0.25f * (p0[2*w] + p0[2*w+1] + p1[2*w] + p1[2*w+1]);
    }
    // (no barrier: B output lives in registers)

    // ---------------- Phase C: g[c][w] = sum_cp qm[cp][w] * M[cp][c] -----------
    // Lane owns c = 2l, 2l+1 (M loads = one coalesced b64); qm row cp is
    // broadcast from lane cp's registers via v_readlane (no LDS, no x-wave sum).
    {
        float acc0[8], acc1[8];
#pragma unroll
        for (int w = 0; w < 8; ++w) { acc0[w] = 0.f; acc1[w] = 0.f; }

        const float* Mp = M + 2 * l;
#pragma unroll 4
        for (int cp = 0; cp < 64; ++cp) {
            const float2 m2 = *reinterpret_cast<const float2*>(Mp + (size_t)cp * 128);
#pragma unroll
            for (int w = 0; w < 8; ++w) {
                float qv = __int_as_float(
                    __builtin_amdgcn_readlane(__float_as_int(qmA[w]), cp));
                acc0[w] += m2.x * qv;
                acc1[w] += m2.y * qv;
            }
        }
#pragma unroll 4
        for (int cp = 0; cp < 64; ++cp) {
            const float2 m2 =
                *reinterpret_cast<const float2*>(Mp + (size_t)(cp + 64) * 128);
#pragma unroll
            for (int w = 0; w < 8; ++w) {
                float qv = __int_as_float(
                    __builtin_amdgcn_readlane(__float_as_int(qmB[w]), cp));
                acc0[w] += m2.x * qv;
                acc1[w] += m2.y * qv;
            }
        }
        // write g rows 2l, 2l+1, cols wv*8..wv*8+7 (16B-aligned, ~8-way only on
        // these 4 insts -> negligible)
        *reinterpret_cast<float4*>(&qg[2*l][wv*8])     = make_float4(acc0[0], acc0[1], acc0[2], acc0[3]);
        *reinterpret_cast<float4*>(&qg[2*l][wv*8+4])   = make_float4(acc0[4], acc0[5], acc0[6], acc0[7]);
        *reinterpret_cast<float4*>(&qg[2*l+1][wv*8])   = make_float4(acc1[0], acc1[1], acc1[2], acc1[3]);
        *reinterpret_cast<float4*>(&qg[2*l+1][wv*8+4]) = make_float4(acc1[4], acc1[5], acc1[6], acc1[7]);
    }
    __syncthreads();

    // ---------------- Phase D: qk + softmax -> attn4 ---------------------------
    {
        const int w    = t >> 3;        // 0..15 (global window)
        const int tsub = t & 7;         // 8 lanes per window
        float qk0 = 0.f, qk1 = 0.f, qk2 = 0.f, qk3 = 0.f;
#pragma unroll
        for (int i = 0; i < 16; ++i) {
            int c = i * 8 + tsub;
            float g = qg[c][w];                       // conflict-free (QS=20)
            const float2 x0 = *reinterpret_cast<const float2*>(&tile[c][2 * w]);
            const float2 x1 = *reinterpret_cast<const float2*>(&tile[c][32 + 2 * w]);
            qk0 += g * x0.x; qk1 += g * x0.y;
            qk2 += g * x1.x; qk3 += g * x1.y;
        }
#pragma unroll
        for (int off = 1; off < 8; off <<= 1) {
            qk0 += __shfl_xor(qk0, off);
            qk1 += __shfl_xor(qk1, off);
            qk2 += __shfl_xor(qk2, off);
            qk3 += __shfl_xor(qk3, off);
        }
        float mx = fmaxf(fmaxf(qk0, qk1), fmaxf(qk2, qk3));
        float e0 = __expf(qk0 - mx);
        float e1 = __expf(qk1 - mx);
        float e2 = __expf(qk2 - mx);
        float e3 = __expf(qk3 - mx);
        float inv = 1.0f / (e0 + e1 + e2 + e3);
        if (tsub == 0)
            attn4[w] = make_float4(e0 * inv, e1 * inv, e2 * inv, e3 * inv);
    }
    __syncthreads();

    // ---------------- Phase E: out; 16 consecutive lanes -> 64B runs (clean) ---
    {
        const int jw = t & 15;
        const int cg = t >> 4;          // 0..7
        const float4 a = attn4[jw];
#pragma unroll
        for (int i = 0; i < 16; ++i) {
            int c = cg * 16 + i;
            const float2 x0 = *reinterpret_cast<const float2*>(&tile[c][2 * jw]);
            const float2 x1 = *reinterpret_cast<const float2*>(&tile[c][32 + 2 * jw]);
            out[(((size_t)(b * CCH + c)) * NHH + nh) * NWW + wseg * 16 + jw] =
                a.x * x0.x + a.y * x0.y + a.z * x1.x + a.w * x1.y;
        }
    }
}

extern "C" void kernel_launch(void* const* d_in, const int* in_sizes, int n_in,
                              void* d_out, int out_size, void* d_ws, size_t ws_size,
                              hipStream_t stream) {
    const float* fm = (const float*)d_in[0];
    const float* Wq = (const float*)d_in[1];
    const float* Wk = (const float*)d_in[2];
    float* outp = (float*)d_out;
    float* Mws  = (float*)d_ws;      // 128*128 floats = 64 KB

    compute_m_kernel<<<dim3(64), dim3(256), 0, stream>>>(Wq, Wk, Mws);

    dim3 grid(NWW / WPB, NHH, BB);   // (8, 128, 8)
    attn_ds3<<<grid, dim3(TPB), 0, stream>>>(fm, Mws, outp);
}

// Round 5
// 417.898 us; speedup vs baseline: 1.3755x; 1.1480x over previous
//
#include <hip/hip_runtime.h>

// Problem constants (fixed by reference setup_inputs)
#define BB   8
#define CCH  128
#define HH   256
#define WW   256
#define NHH  128
#define NWW  128

#define WPB  16          // windows per block (32 input cols)
#define TPB  256         // 4 waves
#define TS   72          // tile row stride (floats): 64 used + 8 pad (bank stride 8)
#define QMS  132         // qmW/gT row stride (floats)

typedef __attribute__((ext_vector_type(8))) __bf16 bf16x8;
typedef __attribute__((ext_vector_type(4))) float f32x4;

union U16x8 { ushort s[8]; int4 i4; bf16x8 v; };

__device__ __forceinline__ ushort f32_to_bf16_rne(float x) {
    unsigned u = __float_as_uint(x);
    unsigned r = (u + 0x7FFFu + ((u >> 16) & 1u)) >> 16;
    return (ushort)r;
}
__device__ __forceinline__ float bf16_to_f32(ushort h) {
    return __uint_as_float(((unsigned)h) << 16);
}

// Kernel 0: MT_hi/lo[c][cp] = bf16 hi/lo split of (1/sqrt(32)) * (Wq Wk^T)[cp][c]
__global__ void compute_mt_kernel(const float* __restrict__ Wq,
                                  const float* __restrict__ Wk,
                                  ushort* __restrict__ MT_hi,
                                  ushort* __restrict__ MT_lo) {
    int idx = blockIdx.x * blockDim.x + threadIdx.x;   // 0..16383
    int c  = idx >> 7;     // output row (channel c)
    int cp = idx & 127;    // output col (channel c')
    float s = 0.f;
#pragma unroll
    for (int r = 0; r < 32; ++r)
        s += Wq[cp * 32 + r] * Wk[c * 32 + r];
    s *= 0.17677669529663687f;          // 32^-0.5
    ushort hi = f32_to_bf16_rne(s);
    float  rem = s - bf16_to_f32(hi);
    ushort lo = f32_to_bf16_rne(rem);
    MT_hi[c * 128 + cp] = hi;
    MT_lo[c * 128 + cp] = lo;
}

__global__ __launch_bounds__(TPB)
void attn_ds5(const float* __restrict__ fm,
              const ushort* __restrict__ MT_hi,
              const ushort* __restrict__ MT_lo,
              float* __restrict__ out) {
    // tile[c][(w<<2)|tok], tok = (r<<1)|(j&1): 4-token groups -> b128 per (c,w)
    __shared__ float tile[CCH][TS];      // 36864 B
    __shared__ float qmW[WPB][QMS];      // 8448 B: qm[w][cp]; aliased as gT[w][c] after C
    __shared__ float4 attn4[WPB];        // 256 B

    const int wseg = blockIdx.x;         // 0..7
    const int nh   = blockIdx.y;         // 0..127
    const int b    = blockIdx.z;         // 0..7
    const int t    = threadIdx.x;        // 0..255
    const int l    = t & 63;
    const int wv   = t >> 6;             // wave 0..3

    // ---------------- Phase A: stage 128c x 64 px, token-grouped ----------------
    {
        const float* fmb = fm + ((size_t)(b * CCH) * HH + nh * 2) * WW + wseg * 32;
#pragma unroll
        for (int k = 0; k < 8; ++k) {
            int q  = k * TPB + t;        // float4 index 0..2047
            int c  = q >> 4;             // 16 float4 per c-row (2 rows x 32 cols)
            int f  = q & 15;
            int r  = f >> 3;             // input row within window pair
            int j4 = (f & 7) << 2;       // col 0..28
            const float4 v = *reinterpret_cast<const float4*>(
                fm + 0 * 0 + (size_t)0 + (fmb - fm) + ((size_t)c * HH + r) * WW + j4);
            float vv[4] = {v.x, v.y, v.z, v.w};
#pragma unroll
            for (int i = 0; i < 4; ++i) {
                int jj  = j4 + i;
                int w   = jj >> 1;
                int tok = (r << 1) | (jj & 1);
                tile[c][(w << 2) | tok] = vv[i];
            }
        }
    }
    __syncthreads();

    // ---------------- Phase B: qmW[w][c] = mean of 4 tokens ---------------------
    {
        const int c     = t & 127;
        const int whalf = t >> 7;        // 0 or 1 (8 windows each)
#pragma unroll
        for (int k = 0; k < 8; ++k) {
            int w = whalf * 8 + ((k + (c & 7)) & 7);   // rotated to spread banks
            const float4 x4 = *reinterpret_cast<const float4*>(&tile[c][w << 2]);
            qmW[w][c] = 0.25f * (x4.x + x4.y + x4.z + x4.w);
        }
    }
    __syncthreads();

    // ---------------- Phase C: g = qm @ M via bf16 hi/lo MFMA -------------------
    // D[w][c] = sum_cp A[w][cp] * B[cp][c];  A = qmW (16x128), B = M (128x128).
    // Wave wv owns c-tiles {2wv, 2wv+1} (16 cols each).
    {
        const int wrow = l & 15;         // A row (w) / B,D col (c within tile)
        const int lq   = l >> 4;         // 0..3
        f32x4 acc0 = {0.f, 0.f, 0.f, 0.f};
        f32x4 acc1 = {0.f, 0.f, 0.f, 0.f};
        const int ct0 = 2 * wv, ct1 = 2 * wv + 1;

#pragma unroll
        for (int kk = 0; kk < 4; ++kk) {
            // A-fragment: qmW[wrow][kk*32 + lq*8 + j], j=0..7, f32 -> hi/lo bf16
            const float* ap = &qmW[wrow][kk * 32 + lq * 8];
            const float4 a0 = *reinterpret_cast<const float4*>(ap);
            const float4 a1 = *reinterpret_cast<const float4*>(ap + 4);
            float af[8] = {a0.x, a0.y, a0.z, a0.w, a1.x, a1.y, a1.z, a1.w};
            U16x8 Ah, Al;
#pragma unroll
            for (int j = 0; j < 8; ++j) {
                ushort hi = f32_to_bf16_rne(af[j]);
                Ah.s[j] = hi;
                Al.s[j] = f32_to_bf16_rne(af[j] - bf16_to_f32(hi));
            }
            // B-fragments: MT[ct*16+wrow][kk*32 + lq*8 + j] (contiguous bf16 x8)
            const size_t bo0 = (size_t)(ct0 * 16 + wrow) * 128 + kk * 32 + lq * 8;
            const size_t bo1 = (size_t)(ct1 * 16 + wrow) * 128 + kk * 32 + lq * 8;
            U16x8 Bh0, Bl0, Bh1, Bl1;
            Bh0.i4 = *reinterpret_cast<const int4*>(MT_hi + bo0);
            Bl0.i4 = *reinterpret_cast<const int4*>(MT_lo + bo0);
            Bh1.i4 = *reinterpret_cast<const int4*>(MT_hi + bo1);
            Bl1.i4 = *reinterpret_cast<const int4*>(MT_lo + bo1);

            acc0 = __builtin_amdgcn_mfma_f32_16x16x32_bf16(Ah.v, Bh0.v, acc0, 0, 0, 0);
            acc0 = __builtin_amdgcn_mfma_f32_16x16x32_bf16(Ah.v, Bl0.v, acc0, 0, 0, 0);
            acc0 = __builtin_amdgcn_mfma_f32_16x16x32_bf16(Al.v, Bh0.v, acc0, 0, 0, 0);
            acc1 = __builtin_amdgcn_mfma_f32_16x16x32_bf16(Ah.v, Bh1.v, acc1, 0, 0, 0);
            acc1 = __builtin_amdgcn_mfma_f32_16x16x32_bf16(Ah.v, Bl1.v, acc1, 0, 0, 0);
            acc1 = __builtin_amdgcn_mfma_f32_16x16x32_bf16(Al.v, Bh1.v, acc1, 0, 0, 0);
        }
        __syncthreads();   // all qmW reads done before gT overwrite (aliased)

        // D-fragment: lane holds D[w = lq*4+r][c = ct*16+wrow] -> gT[w][c]
#pragma unroll
        for (int r = 0; r < 4; ++r) {
            qmW[lq * 4 + r][ct0 * 16 + wrow] = acc0[r];
            qmW[lq * 4 + r][ct1 * 16 + wrow] = acc1[r];
        }
    }
    __syncthreads();

    // ---------------- Phase D: qk + softmax -> attn4 ----------------------------
    {
        const int w    = t >> 4;         // 0..15
        const int tsub = t & 15;         // 16 lanes per window
        float qk0 = 0.f, qk1 = 0.f, qk2 = 0.f, qk3 = 0.f;
#pragma unroll
        for (int i = 0; i < 8; ++i) {
            int c = i * 16 + tsub;
            float g = qmW[w][c];                       // gT
            const float4 x4 = *reinterpret_cast<const float4*>(&tile[c][w << 2]);
            qk0 += g * x4.x; qk1 += g * x4.y;
            qk2 += g * x4.z; qk3 += g * x4.w;
        }
#pragma unroll
        for (int off = 1; off < 16; off <<= 1) {
            qk0 += __shfl_xor(qk0, off);
            qk1 += __shfl_xor(qk1, off);
            qk2 += __shfl_xor(qk2, off);
            qk3 += __shfl_xor(qk3, off);
        }
        float mx = fmaxf(fmaxf(qk0, qk1), fmaxf(qk2, qk3));
        float e0 = __expf(qk0 - mx);
        float e1 = __expf(qk1 - mx);
        float e2 = __expf(qk2 - mx);
        float e3 = __expf(qk3 - mx);
        float inv = 1.0f / (e0 + e1 + e2 + e3);
        if (tsub == 0)
            attn4[w] = make_float4(e0 * inv, e1 * inv, e2 * inv, e3 * inv);
    }
    __syncthreads();

    // ---------------- Phase E: out (16-lane-contiguous scalar stores) -----------
    {
        const int jw = t & 15;
        const int cg = t >> 4;           // 0..15
        const float4 a = attn4[jw];
#pragma unroll
        for (int i = 0; i < 8; ++i) {
            int c = cg * 8 + i;
            const float4 x4 = *reinterpret_cast<const float4*>(&tile[c][jw << 2]);
            float o = a.x * x4.x + a.y * x4.y + a.z * x4.z + a.w * x4.w;
            out[(((size_t)(b * CCH + c)) * NHH + nh) * NWW + wseg * 16 + jw] = o;
        }
    }
}

extern "C" void kernel_launch(void* const* d_in, const int* in_sizes, int n_in,
                              void* d_out, int out_size, void* d_ws, size_t ws_size,
                              hipStream_t stream) {
    const float* fm = (const float*)d_in[0];
    const float* Wq = (const float*)d_in[1];
    const float* Wk = (const float*)d_in[2];
    float* outp = (float*)d_out;
    ushort* MT_hi = (ushort*)d_ws;                 // 128*128 bf16 = 32 KB
    ushort* MT_lo = (ushort*)d_ws + 128 * 128;     // 32 KB

    compute_mt_kernel<<<dim3(64), dim3(256), 0, stream>>>(Wq, Wk, MT_hi, MT_lo);

    dim3 grid(NWW / WPB, NHH, BB);   // (8, 128, 8)
    attn_ds5<<<grid, dim3(TPB), 0, stream>>>(fm, MT_hi, MT_lo, outp);
}